// Round 12
// baseline (272.503 us; speedup 1.0000x reference)
//
#include <hip/hip_runtime.h>

// GraphAttentionLayer, MI355X (gfx950). All fp32 in/out.
// out = 0.5 * softmax_row(cos(xn,yn) + (1-adj)*NEG) @ y + 0.5 * x
//
// R12 = R11's verified math with a T3/T4 counted-vmcnt pipeline:
//  - 32-j tiles, TRIPLE-buffered Y/Yt LDS; stage(t+2) issued at top of t.
//  - raw s_barrier + s_waitcnt vmcnt(4) (never 0 in steady state): the
//    newest stage stays in flight across the barrier (m201 pattern).
//  - adj bitmasks staged into LDS once (XOR-swizzled, conflict-free ds_read)
//    so the K-loop contains ZERO compiler-tracked global loads -> compiler
//    cannot emit a pipeline-draining vmcnt(0).
//  - s_setprio(1) around MFMA clusters (T5).

typedef short bf16x8 __attribute__((ext_vector_type(8)));
typedef float f32x16 __attribute__((ext_vector_type(16)));

static constexpr float EPSF = 1e-8f;
static constexpr float LOG2E = 1.44269504088896340736f;

__device__ __forceinline__ unsigned short f2bf(float f) {
    union { float f; unsigned int i; } v; v.f = f;
    return (unsigned short)((v.i + 0x7FFFu + ((v.i >> 16) & 1u)) >> 16);
}

// ---------- prepass: adj -> u32 bitmask words, row-XOR-swizzled ----------
// word for (row, c) stored at row*(M/32) + (c&~31) + ((c&31) ^ (row&31))
__global__ __launch_bounds__(256) void prep_mask(const float* __restrict__ adj,
                                                 unsigned* __restrict__ msk,
                                                 int N, int M) {
    long long total = (long long)N * (M >> 5);
    long long stride = (long long)gridDim.x * blockDim.x;
    int wpr = M >> 5;   // words per row (=256)
    for (long long it = (long long)blockIdx.x * blockDim.x + threadIdx.x;
         it < total; it += stride) {
        int row = (int)(it >> 8);
        int c = (int)(it & 255);
        const float* ap = adj + (size_t)row * M + c * 32;
        unsigned m = 0;
#pragma unroll
        for (int q = 0; q < 8; ++q) {
            float4 a = *(const float4*)(ap + q * 4);
            m |= (a.x != 0.0f ? 1u : 0u) << (4 * q);
            m |= (a.y != 0.0f ? 1u : 0u) << (4 * q + 1);
            m |= (a.z != 0.0f ? 1u : 0u) << (4 * q + 2);
            m |= (a.w != 0.0f ? 1u : 0u) << (4 * q + 3);
        }
        msk[(size_t)row * wpr + (c & ~31) + ((c & 31) ^ (row & 31))] = m;
    }
}

// ---------- prepass: xhat (plain row-major normalized bf16) ----------
__global__ __launch_bounds__(256) void prep_x(const float* __restrict__ x,
                                              unsigned short* __restrict__ xhat, int N) {
    int row = (int)((blockIdx.x * blockDim.x + threadIdx.x) >> 6);
    int lane = threadIdx.x & 63;
    if (row >= N) return;
    float4 v = *(const float4*)(x + (size_t)row * 256 + lane * 4);
    float ss = v.x * v.x + v.y * v.y + v.z * v.z + v.w * v.w;
#pragma unroll
    for (int o = 1; o < 64; o <<= 1) ss += __shfl_xor(ss, o, 64);
    float inv = 1.0f / fmaxf(sqrtf(ss), EPSF);
    ushort4 b = { f2bf(v.x * inv), f2bf(v.y * inv), f2bf(v.z * inv), f2bf(v.w * inv) };
    *(ushort4*)(xhat + (size_t)row * 256 + lane * 4) = b;
}

// ---------- prepass: yswz (normalized, 32-row tiles, swizzled) ----------
__global__ __launch_bounds__(256) void prep_y(const float* __restrict__ y,
                                              char* __restrict__ yswz, int M) {
    int row = (int)((blockIdx.x * blockDim.x + threadIdx.x) >> 6);
    int lane = threadIdx.x & 63;
    if (row >= M) return;
    float4 v = *(const float4*)(y + (size_t)row * 256 + lane * 4);
    float ss = v.x * v.x + v.y * v.y + v.z * v.z + v.w * v.w;
#pragma unroll
    for (int o = 1; o < 64; o <<= 1) ss += __shfl_xor(ss, o, 64);
    float inv = 1.0f / fmaxf(sqrtf(ss), EPSF);
    int jt = row >> 5, r = row & 31;
    int u = lane >> 1, h = lane & 1;           // 32 16B-units per 512B row
    int phys = u ^ r;
    ushort4 b = { f2bf(v.x * inv), f2bf(v.y * inv), f2bf(v.z * inv), f2bf(v.w * inv) };
    *(ushort4*)(yswz + (size_t)jt * 16384 + r * 512 + phys * 16 + h * 8) = b;
}

// ---------- prepass: ytswz = bf16(y^T), [jt32][256 n][4 units] swizzled ----
__global__ __launch_bounds__(256) void prep_yt(const float* __restrict__ y,
                                               char* __restrict__ ytswz, int M) {
    int t = blockIdx.x * blockDim.x + threadIdx.x;
    int np = t & 255;
    int up = (t >> 8) & 3;
    int jt = t >> 10;
    if (jt >= (M >> 5)) return;
    const float* yb = y + (size_t)(jt * 32 + up * 8) * 256 + np;
    unsigned w0 = (unsigned)f2bf(yb[0])    | ((unsigned)f2bf(yb[256])  << 16);
    unsigned w1 = (unsigned)f2bf(yb[512])  | ((unsigned)f2bf(yb[768])  << 16);
    unsigned w2 = (unsigned)f2bf(yb[1024]) | ((unsigned)f2bf(yb[1280]) << 16);
    unsigned w3 = (unsigned)f2bf(yb[1536]) | ((unsigned)f2bf(yb[1792]) << 16);
    uint4 out = { w0, w1, w2, w3 };
    *(uint4*)(ytswz + (size_t)jt * 16384 + np * 64 + ((up ^ (np & 3)) << 4)) = out;
}

// ---------- main ----------
#define GLD16(gp, lp) __builtin_amdgcn_global_load_lds( \
    (const __attribute__((address_space(1))) unsigned int*)(gp), \
    (__attribute__((address_space(3))) unsigned int*)(lp), 16, 0, 0)

#define PKSWAP(E, TAU, W) { \
    unsigned X0, X1, Y0, Y1; \
    asm("v_cvt_pk_bf16_f32 %0, %1, %2" : "=v"(X0) : "v"(E[8*TAU+0]), "v"(E[8*TAU+1])); \
    asm("v_cvt_pk_bf16_f32 %0, %1, %2" : "=v"(X1) : "v"(E[8*TAU+2]), "v"(E[8*TAU+3])); \
    asm("v_cvt_pk_bf16_f32 %0, %1, %2" : "=v"(Y0) : "v"(E[8*TAU+4]), "v"(E[8*TAU+5])); \
    asm("v_cvt_pk_bf16_f32 %0, %1, %2" : "=v"(Y1) : "v"(E[8*TAU+6]), "v"(E[8*TAU+7])); \
    asm("v_permlane32_swap_b32 %0, %1" : "+v"(X0), "+v"(Y0)); \
    asm("v_permlane32_swap_b32 %0, %1" : "+v"(X1), "+v"(Y1)); \
    W[0] = X0; W[1] = X1; W[2] = Y0; W[3] = Y1; }

__global__ __launch_bounds__(512, 2) void gat_main(
        const unsigned short* __restrict__ xhat,
        const char* __restrict__ yswz,
        const char* __restrict__ ytswz,
        const unsigned* __restrict__ msk,   // [N][M/32] swizzled words
        float* __restrict__ o0,             // jc==0 partial (d_out)
        float* __restrict__ ows,            // jc>=1 partials
        float* __restrict__ zpart,
        int N, int M, int TPB, int js) {
    // LDS: Y 3x16K | Yt 3x16K | masks 32K  = 128 KiB
    __shared__ __align__(16) char lds[131072];

    int tid = threadIdx.x;
    int w = tid >> 6, lane = tid & 63;
    int hi = lane >> 5, lm = lane & 31;
    int lid = (int)blockIdx.x;
    int jc = lid % js;                 // jc->XCD co-location (XCD = id % 8)
    int i0 = (lid / js) * 256;
    int g0 = jc * TPB;
    int wpr = M >> 5;

    // Q-frags: lane holds xhat[i0+w*32+lm][16*kt + 8*hi + 0..7]
    bf16x8 qf[16];
    {
        const char* qb = (const char*)xhat + (size_t)(i0 + w * 32 + lm) * 512 + hi * 16;
#pragma unroll
        for (int kt = 0; kt < 16; ++kt) qf[kt] = *(const bf16x8*)(qb + kt * 32);
    }

    f32x16 o[8];
#pragma unroll
    for (int nt = 0; nt < 8; ++nt) o[nt] = (f32x16)(0.0f);
    float z = 0.0f;

    // stage y tile g into ring buffer b (linear LDS; source pre-swizzled)
    auto stage = [&](int g, int b) {
        const char* ys = yswz + (size_t)g * 16384;
        const char* ts = ytswz + (size_t)g * 16384;
        char* yd = lds + b * 16384;
        char* td = lds + 49152 + b * 16384;
#pragma unroll
        for (int c = 0; c < 2; ++c) {
            int lo = w * 2048 + c * 1024;
            int go = lo + lane * 16;
            GLD16(ys + go, yd + lo);
            GLD16(ts + go, td + lo);
        }
    };
    // stage 32-tile mask window starting at local tile tw (wave-private rows)
    auto stage_mask = [&](int tw) {
        char* md = lds + 98304 + w * 4096;
#pragma unroll
        for (int c = 0; c < 4; ++c) {
            const char* gp = (const char*)msk
                + ((size_t)(i0 + w * 32 + c * 8 + (lane >> 3)) * wpr + (g0 + tw)) * 4
                + (lane & 7) * 16;
            GLD16(gp, md + c * 1024);
        }
    };

    stage_mask(0);
    stage(g0 + 0, 0);
    if (TPB > 1) stage(g0 + 1, 1);
    asm volatile("s_waitcnt vmcnt(4)" ::: "memory");   // mask + stage0 done
    __builtin_amdgcn_s_barrier();

    const unsigned* mbuf = (const unsigned*)(lds + 98304);

    for (int t = 0; t < TPB; ++t) {
        int buf = t % 3;
        // mask window refresh (only reachable when js<8 -> TPB>32)
        if ((t & 31) == 0 && t > 0) {
            asm volatile("s_waitcnt vmcnt(0)" ::: "memory");
            __builtin_amdgcn_s_barrier();
            stage_mask(t);
        }
        if (t + 2 < TPB) stage(g0 + t + 2, (t + 2) % 3);
        if ((t & 31) == 0 && t > 0) {
            asm volatile("s_waitcnt vmcnt(4)" ::: "memory");  // mask ready
        }

        // per-row mask word (conflict-free: bank = (t^lm)&31), lgkm domain
        unsigned mw = mbuf[(w * 32 + lm) * 32 + ((t & 31) ^ lm)];

        // QK^T (swapped): S^T[j-local][m=lm] over K=256
        const char* yb = lds + buf * 16384;
        f32x16 s0 = (f32x16)(0.0f);
        __builtin_amdgcn_s_setprio(1);
#pragma unroll
        for (int kt = 0; kt < 16; ++kt) {
            int phys = (hi + 2 * kt) ^ lm;
            bf16x8 a0 = *(const bf16x8*)(yb + lm * 512 + phys * 16);
            s0 = __builtin_amdgcn_mfma_f32_32x32x16_bf16(a0, qf[kt], s0, 0, 0, 0);
        }
        __builtin_amdgcn_s_setprio(0);

        // mask + exp(cos-1) + Z, in place into s0
        float zl = 0.0f;
#pragma unroll
        for (int rg = 0; rg < 16; ++rg) {
            int jl = (rg & 3) + 8 * (rg >> 2) + 4 * hi;
            float x0 = __builtin_exp2f(__builtin_fmaf(s0[rg], LOG2E, -LOG2E));
            s0[rg] = ((mw >> jl) & 1u) ? x0 : 0.0f;
            zl += s0[rg];
        }
        z += zl;

        // P -> PV A-frags in-register (cvt_pk + permlane32_swap)
        unsigned pw0[4], pw1[4];
        PKSWAP(s0, 0, pw0); PKSWAP(s0, 1, pw1);
        bf16x8 paf[2];
        { uint4 q = { pw0[0], pw0[1], pw0[2], pw0[3] }; paf[0] = __builtin_bit_cast(bf16x8, q); }
        { uint4 q = { pw1[0], pw1[1], pw1[2], pw1[3] }; paf[1] = __builtin_bit_cast(bf16x8, q); }

        // PV: O[m][n'] += P[m][k'] * yT[n'][k']
        const char* tb = lds + 49152 + buf * 16384;
        __builtin_amdgcn_s_setprio(1);
#pragma unroll
        for (int nt = 0; nt < 8; ++nt) {
            int np = nt * 32 + lm;
#pragma unroll
            for (int tp = 0; tp < 2; ++tp) {
                int phys = (hi + 2 * tp) ^ (np & 3);
                bf16x8 bfr = *(const bf16x8*)(tb + np * 64 + phys * 16);
                o[nt] = __builtin_amdgcn_mfma_f32_32x32x16_bf16(paf[tp], bfr, o[nt], 0, 0, 0);
            }
        }
        __builtin_amdgcn_s_setprio(0);

        // counted-vmcnt barrier: only the OLD stage must land; the newest
        // 4 loads (tile t+2) stay in flight across the barrier.
        if (t + 1 < TPB) {
            if (t + 2 < TPB) {
                asm volatile("s_waitcnt vmcnt(4)" ::: "memory");
            } else {
                asm volatile("s_waitcnt vmcnt(0)" ::: "memory");
            }
            __builtin_amdgcn_s_barrier();
        }
    }

    // Z partial (hi halves hold complementary j subsets)
    z += __shfl_xor(z, 32, 64);
    if (lane < 32) zpart[(size_t)jc * N + i0 + w * 32 + lane] = z;

    float* ob = (jc == 0) ? o0 : (ows + (size_t)(jc - 1) * N * 256);
#pragma unroll
    for (int nt = 0; nt < 8; ++nt) {
#pragma unroll
        for (int rg = 0; rg < 16; ++rg) {
            int m = (rg & 3) + 8 * (rg >> 2) + 4 * hi;
            ob[(size_t)(i0 + w * 32 + m) * 256 + nt * 32 + lm] = o[nt][rg];
        }
    }
}

// ---------- reductions ----------
__global__ __launch_bounds__(256) void zred(const float* __restrict__ zpart,
                                            float* __restrict__ zinv, int N, int js) {
    int i = blockIdx.x * 256 + threadIdx.x;
    if (i >= N) return;
    float s = 0.0f;
    for (int jc = 0; jc < js; ++jc) s += zpart[(size_t)jc * N + i];
    zinv[i] = 0.5f / s;
}

__global__ __launch_bounds__(256) void fin(float* __restrict__ out,
                                           const float* __restrict__ ows,
                                           const float* __restrict__ zinv,
                                           const float* __restrict__ x,
                                           int N, int js) {
    int gid = blockIdx.x * 256 + threadIdx.x;     // one float4 each
    if (gid >= N * 64) return;
    int i = gid >> 6;
    float4 a = ((const float4*)out)[gid];
    for (int jc = 1; jc < js; ++jc) {
        float4 p = ((const float4*)(ows + (size_t)(jc - 1) * N * 256))[gid];
        a.x += p.x; a.y += p.y; a.z += p.z; a.w += p.w;
    }
    float zi = zinv[i];
    float4 xv = ((const float4*)x)[gid];
    float4 r;
    r.x = a.x * zi + 0.5f * xv.x;
    r.y = a.y * zi + 0.5f * xv.y;
    r.z = a.z * zi + 0.5f * xv.z;
    r.w = a.w * zi + 0.5f * xv.w;
    ((float4*)out)[gid] = r;
}

extern "C" void kernel_launch(void* const* d_in, const int* in_sizes, int n_in,
                              void* d_out, int out_size, void* d_ws, size_t ws_size,
                              hipStream_t stream) {
    const float* x = (const float*)d_in[0];
    const float* y = (const float*)d_in[1];
    const float* adj = (const float*)d_in[2];
    float* out = (float*)d_out;

    const int D = 256;
    int N = in_sizes[0] / D;
    int M = in_sizes[1] / D;

    char* w = (char*)d_ws;
    unsigned short* xhat = (unsigned short*)w;                       // N*512 B
    char* yswz  = w + (size_t)N * 512;                               // M*512 B
    char* ytswz = w + (size_t)N * 512 + (size_t)M * 512;             // M*512 B
    unsigned* msk = (unsigned*)(w + (size_t)N * 512 + 2 * (size_t)M * 512);
    size_t base = (size_t)N * 512 + 2 * (size_t)M * 512
                + (size_t)N * (size_t)(M / 32) * 4;                  // + masks

    int js = 1;
    {
        int cands[4] = { 8, 4, 2, 1 };
        for (int k = 0; k < 4; ++k) {
            int c = cands[k];
            size_t need = base + (size_t)(c + 1) * N * 4 +           // zpart + zinv
                          (size_t)(c - 1) * N * 1024;                // O partials
            if (ws_size >= need) { js = c; break; }
        }
    }
    float* zpart = (float*)(w + base);
    float* zinv  = zpart + (size_t)js * N;
    float* ows   = zinv + N;
    int TPB = (M / 32) / js;

    prep_mask<<<2048, 256, 0, stream>>>(adj, msk, N, M);
    prep_x<<<(N + 3) / 4, 256, 0, stream>>>(x, xhat, N);
    prep_y<<<(M + 3) / 4, 256, 0, stream>>>(y, yswz, M);
    prep_yt<<<((M / 32) * 1024 + 255) / 256, 256, 0, stream>>>(y, ytswz, M);
    gat_main<<<(N / 256) * js, 512, 0, stream>>>(xhat, yswz, ytswz, msk,
                                                 out, ows, zpart, N, M, TPB, js);
    zred<<<(N + 255) / 256, 256, 0, stream>>>(zpart, zinv, N, js);
    fin<<<(N * 64 + 255) / 256, 256, 0, stream>>>(out, ows, zinv, x, N, js);
}